// Round 2
// baseline (427.144 us; speedup 1.0000x reference)
//
#include <hip/hip_runtime.h>
#include <hip/hip_bf16.h>
#include <math.h>
#include <stdint.h>

#define B 2
#define H 16
#define L 2048
#define D 64
#define NB 32
#define PTS 72            // P tile row stride in u16 (144 B)

typedef unsigned short u16;
typedef unsigned int u32;
typedef __attribute__((ext_vector_type(2))) unsigned int u32x2;
typedef __attribute__((ext_vector_type(4))) unsigned int u32x4;
typedef __attribute__((ext_vector_type(8))) short s16x8;
typedef __attribute__((ext_vector_type(4))) float f32x4;

union FragU { s16x8 v; u32 u[4]; };

__device__ __forceinline__ u32 pkbf(float a, float b) {
  __hip_bfloat162 h = __float22bfloat162_rn(make_float2(a, b));  // v_cvt_pk_bf16_f32
  union { __hip_bfloat162 h; u32 u; } cv; cv.h = h; return cv.u;
}
__device__ __forceinline__ float bf2f(u32 u16bits) {
  union { u32 u; float f; } c; c.u = u16bits << 16; return c.f;
}
// split float4 -> packed hi (u32x2) + lo (u32x2), RNE both levels
__device__ __forceinline__ void split4(float4 p, u32x2& hi, u32x2& lo) {
  u32 h01 = pkbf(p.x, p.y), h23 = pkbf(p.z, p.w);
  float rx = p.x - bf2f(h01 & 0xffffu);
  float ry = p.y - bf2f(h01 >> 16);
  float rz = p.z - bf2f(h23 & 0xffffu);
  float rw = p.w - bf2f(h23 >> 16);
  hi = (u32x2){h01, h23};
  lo = (u32x2){pkbf(rx, ry), pkbf(rz, rw)};
}

// ---------------------------------------------------------------------------
// k_prep: single pass over K (split + column sums fused), V transpose split.
// 16 B stores on all four bf16 planes. Per-(bh,j) max ||k_row||^2.
// ---------------------------------------------------------------------------
__global__ __launch_bounds__(256) void k_prep(const float* __restrict__ k,
                                              const float* __restrict__ v,
                                              float* __restrict__ ksum,
                                              u16* __restrict__ khi_g,
                                              u16* __restrict__ klo_g,
                                              u16* __restrict__ vthi_g,
                                              u16* __restrict__ vtlo_g,
                                              float* __restrict__ kbmax) {
  int blk = blockIdx.x, bh = blk >> 5, j = blk & 31, t = threadIdx.x;
  int lane = t & 63, w = t >> 6;
  __shared__ float vt[64 * 65];
  __shared__ float pk_[4][64];
  __shared__ unsigned bmaxS;
  if (t == 0) bmaxS = 0u;
  size_t base = (size_t)blk * 4096;

  int r0 = t >> 3;          // 0..31
  int c8 = (t & 7) * 8;     // 0..56
  float cs[8] = {0.f, 0.f, 0.f, 0.f, 0.f, 0.f, 0.f, 0.f};
  float rmax = 0.f;
#pragma unroll
  for (int it = 0; it < 2; ++it) {
    int r = r0 + 32 * it;
    const float* kp = k + base + r * 64 + c8;
    float4 f0 = *(const float4*)kp;
    float4 f1 = *(const float4*)(kp + 4);
    u32x2 h0, l0, h1, l1;
    split4(f0, h0, l0); split4(f1, h1, l1);
    *(u32x4*)(khi_g + base + r * 64 + c8) = (u32x4){h0[0], h0[1], h1[0], h1[1]};
    *(u32x4*)(klo_g + base + r * 64 + c8) = (u32x4){l0[0], l0[1], l1[0], l1[1]};
    cs[0] += f0.x; cs[1] += f0.y; cs[2] += f0.z; cs[3] += f0.w;
    cs[4] += f1.x; cs[5] += f1.y; cs[6] += f1.z; cs[7] += f1.w;
    float ssq = f0.x*f0.x + f0.y*f0.y + f0.z*f0.z + f0.w*f0.w
              + f1.x*f1.x + f1.y*f1.y + f1.z*f1.z + f1.w*f1.w;
    ssq += __shfl_xor(ssq, 1); ssq += __shfl_xor(ssq, 2); ssq += __shfl_xor(ssq, 4);
    if ((t & 7) == 0) rmax = fmaxf(rmax, ssq);
    const float* vp = v + base + r * 64 + c8;
    float4 g0 = *(const float4*)vp;
    float4 g1 = *(const float4*)(vp + 4);
    vt[(c8 + 0) * 65 + r] = g0.x;
    vt[(c8 + 1) * 65 + r] = g0.y;
    vt[(c8 + 2) * 65 + r] = g0.z;
    vt[(c8 + 3) * 65 + r] = g0.w;
    vt[(c8 + 4) * 65 + r] = g1.x;
    vt[(c8 + 5) * 65 + r] = g1.y;
    vt[(c8 + 6) * 65 + r] = g1.z;
    vt[(c8 + 7) * 65 + r] = g1.w;
  }
  if ((t & 7) == 0) atomicMax(&bmaxS, __float_as_uint(rmax));
  // column-sum reduce over r-groups: xor 8/16/32 keep lane&7 (the column group)
#pragma unroll
  for (int i = 0; i < 8; ++i) {
    cs[i] += __shfl_xor(cs[i], 8);
    cs[i] += __shfl_xor(cs[i], 16);
    cs[i] += __shfl_xor(cs[i], 32);
  }
  if (lane < 8) {
    *(float4*)&pk_[w][lane * 8]     = (float4){cs[0], cs[1], cs[2], cs[3]};
    *(float4*)&pk_[w][lane * 8 + 4] = (float4){cs[4], cs[5], cs[6], cs[7]};
  }
  __syncthreads();
  if (t < 64) ksum[(size_t)blk * 64 + t] = pk_[0][t] + pk_[1][t] + pk_[2][t] + pk_[3][t];
  if (t == 0) kbmax[blk] = __uint_as_float(bmaxS);
#pragma unroll
  for (int it = 0; it < 2; ++it) {
    int idx = t + 256 * it, d = idx >> 3, s8 = (idx & 7) * 8;
    const float* vr = &vt[d * 65 + s8];
    float4 f0 = {vr[0], vr[1], vr[2], vr[3]};
    float4 f1 = {vr[4], vr[5], vr[6], vr[7]};
    u32x2 h0, l0, h1, l1;
    split4(f0, h0, l0); split4(f1, h1, l1);
    size_t o = (size_t)bh * 131072 + (size_t)d * 2048 + j * 64 + s8;
    *(u32x4*)(vthi_g + o) = (u32x4){h0[0], h0[1], h1[0], h1[1]};
    *(u32x4*)(vtlo_g + o) = (u32x4){l0[0], l0[1], l1[0], l1[1]};
  }
}

// ---------------------------------------------------------------------------
// k_attn: ONE q-block (64 rows) per WG, 4 waves, each wave owns 16 q-rows.
// Wave-local lse/rowmax (shuffle over kcol lanes), wave-private P transpose
// through LDS -> ZERO barriers in both main loops. 1024 WGs = 4 WGs/CU
// (LDS 27.7 KB), occupancy cap 50% vs previous 25%.
// XCD swizzle: each XCD owns 4 contiguous bh slices.
// LDS (bytes): P 0..18432 (per wave 4608: hi 2304 | lo 2304)
//   rbm 18432 (64*33 f32, 8448)  MS 26880  linv 27136  qm 27392  flg 27648
// ---------------------------------------------------------------------------
__global__ __launch_bounds__(256, 4) void k_attn(
    const float* __restrict__ q,
    const float* __restrict__ ksum,
    const u16* __restrict__ khi_g, const u16* __restrict__ klo_g,
    const u16* __restrict__ vthi_g, const u16* __restrict__ vtlo_g,
    const float* __restrict__ cdfthreshd, const float* __restrict__ simthreshd1,
    const float* __restrict__ pvthreshd, const float* __restrict__ kbmax,
    float* __restrict__ out) {
  int blk0 = blockIdx.x;
  int blk = (blk0 & 7) * 128 + (blk0 >> 3);   // bijective: 1024 % 8 == 0
  int bh = blk >> 5, iq = blk & 31, h = bh & (H - 1);
  int t = threadIdx.x, lane = t & 63, w = t >> 6;
  int m16 = lane & 15, quad = lane >> 4;

  __shared__ __align__(16) uint8_t smem[27680];
  u16*   pbase = (u16*)smem;                    // wave w: hi @ w*4608 B, lo @ +2304 B
  float* rbm   = (float*)(smem + 18432);        // [64][33]
  float* MSs   = (float*)(smem + 26880);        // [64]
  float* linvS = (float*)(smem + 27136);        // [64]
  float* qmS   = (float*)(smem + 27392);        // [64]
  int*   flg   = (int*)(smem + 27648);          // [0]=pooled [1]=mw [2]=gm [3]=kmax2(f)

  const float* qg = q + ((size_t)bh * L + (size_t)iq * 64) * D;
  const u16* kh = khi_g + (size_t)bh * (L * D);
  const u16* kl = klo_g + (size_t)bh * (L * D);
  const u16* vh = vthi_g + (size_t)bh * (L * D);
  const u16* vl = vtlo_g + (size_t)bh * (L * D);

  // ---- Q A-frags: wave w owns q-rows 16w..16w+15; lane holds A[m16][quad*8+e]
  s16x8 qh[2], ql[2];
#pragma unroll
  for (int ks = 0; ks < 2; ++ks) {
    const float* p0 = qg + (size_t)(16 * w + m16) * 64 + ks * 32 + quad * 8;
    float4 a = *(const float4*)p0;
    float4 b2 = *(const float4*)(p0 + 4);
    u32x2 ha, la, hb, lb;
    split4(a, ha, la); split4(b2, hb, lb);
    FragU fh, fl;
    fh.u[0] = ha[0]; fh.u[1] = ha[1]; fh.u[2] = hb[0]; fh.u[3] = hb[1];
    fl.u[0] = la[0]; fl.u[1] = la[1]; fl.u[2] = lb[0]; fl.u[3] = lb[1];
    qh[ks] = fh.v; ql[ks] = fl.v;
  }
  for (int e = t; e < 64 * 33; e += 256) rbm[e] = __builtin_inff();

  // ---- phase 1: qm (w0), kmax2 (w1) ----
  if (w == 0) {
    float s = 0.f;
    for (int r = 0; r < 64; ++r) s += qg[r * 64 + lane];
    qmS[lane] = s * (1.f / 64.f);
  }
  if (w == 1) {
    float m = (lane < 32) ? kbmax[bh * 32 + lane] : 0.f;
    for (int off = 16; off; off >>= 1) m = fmaxf(m, __shfl_xor(m, off, 32));
    if (lane == 0) ((float*)flg)[3] = m;
  }
  __syncthreads();

  // ---- phase 2: CDF keep (w0); pooled cos + M (w1) ----
  bool keepj = false;
  if (w == 0 && lane < 32) {
    int j = lane;
    const float* ksp = ksum + (size_t)bh * NB * 64 + j * 64;
    float sv = 0.f;
    for (int d = 0; d < 64; ++d) sv += qmS[d] * ksp[d];
    sv *= (1.f / 64.f) * 0.125f;
    float mx = sv;
    for (int off = 16; off; off >>= 1) mx = fmaxf(mx, __shfl_xor(mx, off, 32));
    float p = expf(sv - mx);
    float sum = p;
    for (int off = 16; off; off >>= 1) sum += __shfl_xor(sum, off, 32);
    p /= sum;
    float excl = 0.f;
    for (int u = 0; u < 32; ++u) {
      float pu = __shfl(p, u, 32);
      if ((pu > p) || (pu == p && u < j)) excl += pu;
    }
    keepj = excl < cdfthreshd[h];
  }
  if (w == 1) {
    int r = lane;
    float kmax2 = ((float*)flg)[3];
    float dot = 0.f, qn2 = 0.f, qmn2 = 0.f;
    for (int d = 0; d < 64; ++d) {
      float a = qg[r * 64 + d], b2 = qmS[d];
      dot += a * b2; qn2 += a * a; qmn2 += b2 * b2;
    }
    float cs = dot / (sqrtf(qn2) * sqrtf(qmn2) + 1e-6f);
    float su = cs;
    for (int off = 32; off; off >>= 1) su += __shfl_xor(su, off);
    if (lane == 0) flg[0] = (su * (1.f / 64.f)) > simthreshd1[h];
    MSs[r] = sqrtf(qn2 * kmax2) * 0.125f;  // M_r >= |s| (Cauchy-Schwarz)
  }
  __syncthreads();
  if (w == 0 && lane < 32) {
    bool bit = keepj || !flg[0] || (lane == 0);
    unsigned long long bal = __ballot(bit);
    if (lane == 0) flg[1] = (int)(u32)bal;
  }
  __syncthreads();
  u32 mw = (u32)flg[1];

  float Mq[4];
#pragma unroll
  for (int reg = 0; reg < 4; ++reg) Mq[reg] = MSs[16 * w + 4 * quad + reg];

  // ---- Pass A: barrier-free sweep; lane (m16,quad) covers qrow=4q+reg, krow=16kt+m16
  float lp[4] = {0.f, 0.f, 0.f, 0.f};
  {
    u32 rm = mw;
    while (rm) {
      int j = (int)__builtin_ctz(rm); rm &= rm - 1;
      const u16* kbh_ = kh + (size_t)(j * 64) * 64;
      const u16* kbl_ = kl + (size_t)(j * 64) * 64;
      float vmx[4] = {-1e30f, -1e30f, -1e30f, -1e30f};
#pragma unroll
      for (int half = 0; half < 2; ++half) {
        s16x8 kfh[2][2], kfl[2][2];   // [ktp][ks]
#pragma unroll
        for (int ktp = 0; ktp < 2; ++ktp) {
          const u16* rh = kbh_ + (size_t)(16 * (2 * half + ktp) + m16) * 64 + quad * 8;
          const u16* rl = kbl_ + (size_t)(16 * (2 * half + ktp) + m16) * 64 + quad * 8;
#pragma unroll
          for (int ks = 0; ks < 2; ++ks) {
            kfh[ktp][ks] = *(const s16x8*)(rh + ks * 32);
            kfl[ktp][ks] = *(const s16x8*)(rl + ks * 32);
          }
        }
        f32x4 acc[2] = {{0.f,0.f,0.f,0.f},{0.f,0.f,0.f,0.f}};
        __builtin_amdgcn_s_setprio(1);
#pragma unroll
        for (int ks = 0; ks < 2; ++ks)
#pragma unroll
          for (int ktp = 0; ktp < 2; ++ktp) {
            acc[ktp] = __builtin_amdgcn_mfma_f32_16x16x32_bf16(qh[ks], kfh[ktp][ks], acc[ktp], 0, 0, 0);
            acc[ktp] = __builtin_amdgcn_mfma_f32_16x16x32_bf16(qh[ks], kfl[ktp][ks], acc[ktp], 0, 0, 0);
            acc[ktp] = __builtin_amdgcn_mfma_f32_16x16x32_bf16(ql[ks], kfh[ktp][ks], acc[ktp], 0, 0, 0);
          }
        __builtin_amdgcn_s_setprio(0);
#pragma unroll
        for (int ktp = 0; ktp < 2; ++ktp)
#pragma unroll
          for (int reg = 0; reg < 4; ++reg) {
            float s = acc[ktp][reg] * 0.125f - Mq[reg];
            lp[reg] += __expf(s);
            vmx[reg] = fmaxf(vmx[reg], s);
          }
      }
      // rowmax over the 16 kcol lanes (m16 bits), single owner store (no atomics)
#pragma unroll
      for (int reg = 0; reg < 4; ++reg) {
        float v = vmx[reg];
        v = fmaxf(v, __shfl_xor(v, 1));
        v = fmaxf(v, __shfl_xor(v, 2));
        v = fmaxf(v, __shfl_xor(v, 4));
        v = fmaxf(v, __shfl_xor(v, 8));
        if (m16 == 0) rbm[(16 * w + 4 * quad + reg) * 33 + j] = fmaxf(-v, 0.f);
      }
    }
  }
  // ---- wave-local lse -> linq; publish for PV gate ----
  float linq[4];
#pragma unroll
  for (int reg = 0; reg < 4; ++reg) {
    float s = lp[reg];
    s += __shfl_xor(s, 1); s += __shfl_xor(s, 2);
    s += __shfl_xor(s, 4); s += __shfl_xor(s, 8);
    linq[reg] = 1.f / s;
    if (m16 == 0) linvS[16 * w + 4 * quad + reg] = linq[reg];
  }
  __syncthreads();

  // ---- PV gate (w0) ----
  if (w == 0 && lane < 32) {
    bool keep = (mw >> lane) & 1u;
    if (keep && lane != 0) {
      float thr = pvthreshd[h] * 1e-3f;
      float mp = 0.f;
      for (int r = 0; r < 64; ++r) {
        float key = rbm[r * 33 + lane];
        mp = fmaxf(mp, __expf(-key) * linvS[r]);
      }
      keep = mp >= thr;
    }
    unsigned long long bal = __ballot(keep);
    if (lane == 0) flg[2] = (int)(u32)bal;
  }
  __syncthreads();
  u32 gm = (u32)flg[2];

  // ---- Pass B: barrier-free; per j: S -> P (wave-private LDS) -> PV ----
  f32x4 oacc[4];
#pragma unroll
  for (int dt = 0; dt < 4; ++dt) oacc[dt] = (f32x4){0.f, 0.f, 0.f, 0.f};
  u16* phw = pbase + w * 2304;   // hi plane, u16 units (16 rows x PTS)
  u16* plw = phw + 1152;         // lo plane
  {
    u32 rg = gm;
    while (rg) {
      int j = (int)__builtin_ctz(rg); rg &= rg - 1;
      const u16* kbh_ = kh + (size_t)(j * 64) * 64;
      const u16* kbl_ = kl + (size_t)(j * 64) * 64;
#pragma unroll
      for (int half = 0; half < 2; ++half) {
        s16x8 kfh[2][2], kfl[2][2];
#pragma unroll
        for (int ktp = 0; ktp < 2; ++ktp) {
          const u16* rh = kbh_ + (size_t)(16 * (2 * half + ktp) + m16) * 64 + quad * 8;
          const u16* rl = kbl_ + (size_t)(16 * (2 * half + ktp) + m16) * 64 + quad * 8;
#pragma unroll
          for (int ks = 0; ks < 2; ++ks) {
            kfh[ktp][ks] = *(const s16x8*)(rh + ks * 32);
            kfl[ktp][ks] = *(const s16x8*)(rl + ks * 32);
          }
        }
        f32x4 acc[2] = {{0.f,0.f,0.f,0.f},{0.f,0.f,0.f,0.f}};
        __builtin_amdgcn_s_setprio(1);
#pragma unroll
        for (int ks = 0; ks < 2; ++ks)
#pragma unroll
          for (int ktp = 0; ktp < 2; ++ktp) {
            acc[ktp] = __builtin_amdgcn_mfma_f32_16x16x32_bf16(qh[ks], kfh[ktp][ks], acc[ktp], 0, 0, 0);
            acc[ktp] = __builtin_amdgcn_mfma_f32_16x16x32_bf16(qh[ks], kfl[ktp][ks], acc[ktp], 0, 0, 0);
            acc[ktp] = __builtin_amdgcn_mfma_f32_16x16x32_bf16(ql[ks], kfh[ktp][ks], acc[ktp], 0, 0, 0);
          }
        __builtin_amdgcn_s_setprio(0);
        // P = exp(S-M)*linv, split hi/lo, scatter to wave-private [qrow][krow]
#pragma unroll
        for (int ktp = 0; ktp < 2; ++ktp) {
          int kt = 2 * half + ktp;
#pragma unroll
          for (int reg = 0; reg < 4; ++reg) {
            float p = __expf(acc[ktp][reg] * 0.125f - Mq[reg]) * linq[reg];
            union { __hip_bfloat16 b; u16 u; } ch, cl;
            ch.b = __float2bfloat16(p);
            cl.b = __float2bfloat16(p - bf2f(ch.u));
            int off = (4 * quad + reg) * PTS + 16 * kt + m16;
            phw[off] = ch.u;
            plw[off] = cl.u;
          }
        }
      }
      // PV: B-frags from own P region (lgkmcnt ordering, no barrier)
      s16x8 pbh[2], pbl[2];
#pragma unroll
      for (int ks = 0; ks < 2; ++ks) {
        pbh[ks] = *(const s16x8*)(phw + m16 * PTS + ks * 32 + quad * 8);
        pbl[ks] = *(const s16x8*)(plw + m16 * PTS + ks * 32 + quad * 8);
      }
      const u16* vbh_ = vh + (size_t)j * 64;
      const u16* vbl_ = vl + (size_t)j * 64;
#pragma unroll
      for (int dt = 0; dt < 4; ++dt) {
        s16x8 vah[2], val_[2];
        const u16* rh = vbh_ + (size_t)(16 * dt + m16) * L + quad * 8;
        const u16* rl = vbl_ + (size_t)(16 * dt + m16) * L + quad * 8;
#pragma unroll
        for (int ks = 0; ks < 2; ++ks) {
          vah[ks] = *(const s16x8*)(rh + ks * 32);
          val_[ks] = *(const s16x8*)(rl + ks * 32);
        }
        __builtin_amdgcn_s_setprio(1);
#pragma unroll
        for (int ks = 0; ks < 2; ++ks) {
          oacc[dt] = __builtin_amdgcn_mfma_f32_16x16x32_bf16(vah[ks], pbh[ks], oacc[dt], 0, 0, 0);
          oacc[dt] = __builtin_amdgcn_mfma_f32_16x16x32_bf16(val_[ks], pbh[ks], oacc[dt], 0, 0, 0);
          oacc[dt] = __builtin_amdgcn_mfma_f32_16x16x32_bf16(vah[ks], pbl[ks], oacc[dt], 0, 0, 0);
        }
        __builtin_amdgcn_s_setprio(0);
      }
    }
  }

  // ---- store O: lane -> qrow = 16w+m16, d = 16dt+4quad (f32x4 over reg) ----
  float* ob = out + ((size_t)bh * L + (size_t)iq * 64) * D;
#pragma unroll
  for (int dt = 0; dt < 4; ++dt)
    *(f32x4*)(ob + (size_t)(16 * w + m16) * 64 + 16 * dt + 4 * quad) = oacc[dt];
}

// ---------------------------------------------------------------------------
extern "C" void kernel_launch(void* const* d_in, const int* in_sizes, int n_in,
                              void* d_out, int out_size, void* d_ws, size_t ws_size,
                              hipStream_t stream) {
  (void)in_sizes; (void)n_in; (void)out_size; (void)ws_size;
  const float* q   = (const float*)d_in[0];
  const float* k   = (const float*)d_in[1];
  const float* v   = (const float*)d_in[2];
  const float* cdf = (const float*)d_in[3];
  const float* sim = (const float*)d_in[4];
  const float* pvt = (const float*)d_in[5];
  float* out = (float*)d_out;

  uint8_t* w8 = (uint8_t*)d_ws;
  float* ksum  = (float*)w8;                          // 1024*64 f (256 KB)
  float* kbmax = (float*)(w8 + 262144);               // 1024 f (4 KB)
  u16* khi_g  = (u16*)(w8 + 266240);                  // 4 planes x 8 MB
  u16* klo_g  = khi_g + (size_t)B * H * L * D;
  u16* vthi_g = klo_g + (size_t)B * H * L * D;
  u16* vtlo_g = vthi_g + (size_t)B * H * L * D;

  k_prep<<<B * H * NB, 256, 0, stream>>>(k, v, ksum, khi_g, klo_g, vthi_g, vtlo_g, kbmax);
  k_attn<<<B * H * NB, 256, 0, stream>>>(q, ksum, khi_g, klo_g, vthi_g, vtlo_g,
                                         cdf, sim, pvt, kbmax, out);
}

// Round 3
// 239.112 us; speedup vs baseline: 1.7864x; 1.7864x over previous
//
#include <hip/hip_runtime.h>
#include <hip/hip_bf16.h>
#include <math.h>
#include <stdint.h>

#define B 2
#define H 16
#define L 2048
#define D 64
#define NB 32
#define PTS 72            // P tile row stride in u16 (144 B)

typedef unsigned short u16;
typedef unsigned int u32;
typedef __attribute__((ext_vector_type(2))) unsigned int u32x2;
typedef __attribute__((ext_vector_type(4))) unsigned int u32x4;
typedef __attribute__((ext_vector_type(8))) short s16x8;
typedef __attribute__((ext_vector_type(4))) float f32x4;

union FragU { s16x8 v; u32 u[4]; };

__device__ __forceinline__ u32 pkbf(float a, float b) {
  __hip_bfloat162 h = __float22bfloat162_rn(make_float2(a, b));  // v_cvt_pk_bf16_f32
  union { __hip_bfloat162 h; u32 u; } cv; cv.h = h; return cv.u;
}
__device__ __forceinline__ float bf2f(u32 u16bits) {
  union { u32 u; float f; } c; c.u = u16bits << 16; return c.f;
}
// split float4 -> packed hi (u32x2) + lo (u32x2), RNE both levels
__device__ __forceinline__ void split4(float4 p, u32x2& hi, u32x2& lo) {
  u32 h01 = pkbf(p.x, p.y), h23 = pkbf(p.z, p.w);
  float rx = p.x - bf2f(h01 & 0xffffu);
  float ry = p.y - bf2f(h01 >> 16);
  float rz = p.z - bf2f(h23 & 0xffffu);
  float rw = p.w - bf2f(h23 >> 16);
  hi = (u32x2){h01, h23};
  lo = (u32x2){pkbf(rx, ry), pkbf(rz, rw)};
}

// ---------------------------------------------------------------------------
// k_prep: single pass over K (split + column sums fused), V transpose split.
// 16 B stores on all four bf16 planes. Per-(bh,j) max ||k_row||^2.
// ---------------------------------------------------------------------------
__global__ __launch_bounds__(256) void k_prep(const float* __restrict__ k,
                                              const float* __restrict__ v,
                                              float* __restrict__ ksum,
                                              u16* __restrict__ khi_g,
                                              u16* __restrict__ klo_g,
                                              u16* __restrict__ vthi_g,
                                              u16* __restrict__ vtlo_g,
                                              float* __restrict__ kbmax) {
  int blk = blockIdx.x, bh = blk >> 5, j = blk & 31, t = threadIdx.x;
  int lane = t & 63, w = t >> 6;
  __shared__ float vt[64 * 65];
  __shared__ float pk_[4][64];
  __shared__ unsigned bmaxS;
  if (t == 0) bmaxS = 0u;
  size_t base = (size_t)blk * 4096;

  int r0 = t >> 3;          // 0..31
  int c8 = (t & 7) * 8;     // 0..56
  float cs[8] = {0.f, 0.f, 0.f, 0.f, 0.f, 0.f, 0.f, 0.f};
  float rmax = 0.f;
#pragma unroll
  for (int it = 0; it < 2; ++it) {
    int r = r0 + 32 * it;
    const float* kp = k + base + r * 64 + c8;
    float4 f0 = *(const float4*)kp;
    float4 f1 = *(const float4*)(kp + 4);
    u32x2 h0, l0, h1, l1;
    split4(f0, h0, l0); split4(f1, h1, l1);
    *(u32x4*)(khi_g + base + r * 64 + c8) = (u32x4){h0[0], h0[1], h1[0], h1[1]};
    *(u32x4*)(klo_g + base + r * 64 + c8) = (u32x4){l0[0], l0[1], l1[0], l1[1]};
    cs[0] += f0.x; cs[1] += f0.y; cs[2] += f0.z; cs[3] += f0.w;
    cs[4] += f1.x; cs[5] += f1.y; cs[6] += f1.z; cs[7] += f1.w;
    float ssq = f0.x*f0.x + f0.y*f0.y + f0.z*f0.z + f0.w*f0.w
              + f1.x*f1.x + f1.y*f1.y + f1.z*f1.z + f1.w*f1.w;
    ssq += __shfl_xor(ssq, 1); ssq += __shfl_xor(ssq, 2); ssq += __shfl_xor(ssq, 4);
    if ((t & 7) == 0) rmax = fmaxf(rmax, ssq);
    const float* vp = v + base + r * 64 + c8;
    float4 g0 = *(const float4*)vp;
    float4 g1 = *(const float4*)(vp + 4);
    vt[(c8 + 0) * 65 + r] = g0.x;
    vt[(c8 + 1) * 65 + r] = g0.y;
    vt[(c8 + 2) * 65 + r] = g0.z;
    vt[(c8 + 3) * 65 + r] = g0.w;
    vt[(c8 + 4) * 65 + r] = g1.x;
    vt[(c8 + 5) * 65 + r] = g1.y;
    vt[(c8 + 6) * 65 + r] = g1.z;
    vt[(c8 + 7) * 65 + r] = g1.w;
  }
  if ((t & 7) == 0) atomicMax(&bmaxS, __float_as_uint(rmax));
  // column-sum reduce over r-groups: xor 8/16/32 keep lane&7 (the column group)
#pragma unroll
  for (int i = 0; i < 8; ++i) {
    cs[i] += __shfl_xor(cs[i], 8);
    cs[i] += __shfl_xor(cs[i], 16);
    cs[i] += __shfl_xor(cs[i], 32);
  }
  if (lane < 8) {
    *(float4*)&pk_[w][lane * 8]     = (float4){cs[0], cs[1], cs[2], cs[3]};
    *(float4*)&pk_[w][lane * 8 + 4] = (float4){cs[4], cs[5], cs[6], cs[7]};
  }
  __syncthreads();
  if (t < 64) ksum[(size_t)blk * 64 + t] = pk_[0][t] + pk_[1][t] + pk_[2][t] + pk_[3][t];
  if (t == 0) kbmax[blk] = __uint_as_float(bmaxS);
#pragma unroll
  for (int it = 0; it < 2; ++it) {
    int idx = t + 256 * it, d = idx >> 3, s8 = (idx & 7) * 8;
    const float* vr = &vt[d * 65 + s8];
    float4 f0 = {vr[0], vr[1], vr[2], vr[3]};
    float4 f1 = {vr[4], vr[5], vr[6], vr[7]};
    u32x2 h0, l0, h1, l1;
    split4(f0, h0, l0); split4(f1, h1, l1);
    size_t o = (size_t)bh * 131072 + (size_t)d * 2048 + j * 64 + s8;
    *(u32x4*)(vthi_g + o) = (u32x4){h0[0], h0[1], h1[0], h1[1]};
    *(u32x4*)(vtlo_g + o) = (u32x4){l0[0], l0[1], l1[0], l1[1]};
  }
}

// ---------------------------------------------------------------------------
// k_attn: ONE q-block per WG, round-1 dataflow (waves split K-rows, zero
// load duplication). P double-buffered -> 1 barrier per j in Pass B.
// rbm/lpart/qm/MS/linv OVERLAID inside the P region (all dead before the
// first P write). LDS 36.9 KB -> 4 WGs/CU at launch_bounds(256,4).
// LDS map (bytes):
//   P: buf0 hi 0..9216, buf0 lo 9216..18432, buf1 hi 18432.., buf1 lo 27648..
//   overlay (dead before Pass B): rbm u32[64*33] @0 (8448), lpart[256] @8448,
//     qm[64] @9472, MS[64] @9728, linv[64] @9984
//   flg @36864 (separate, live throughout)
// ---------------------------------------------------------------------------
__global__ __launch_bounds__(256, 4) void k_attn(
    const float* __restrict__ q,
    const float* __restrict__ ksum,
    const u16* __restrict__ khi_g, const u16* __restrict__ klo_g,
    const u16* __restrict__ vthi_g, const u16* __restrict__ vtlo_g,
    const float* __restrict__ cdfthreshd, const float* __restrict__ simthreshd1,
    const float* __restrict__ pvthreshd, const float* __restrict__ kbmax,
    float* __restrict__ out) {
  int blk0 = blockIdx.x;
  int blk = (blk0 & 7) * 128 + (blk0 >> 3);   // bijective: 1024 % 8 == 0
  int bh = blk >> 5, iq = blk & 31, h = bh & (H - 1);
  int t = threadIdx.x, lane = t & 63, w = t >> 6;
  int m16 = lane & 15, quad = lane >> 4;

  __shared__ __align__(16) uint8_t smem[36896];
  u16*   pbase = (u16*)smem;                    // P bufs (u16 units)
  u32*   rbm   = (u32*)smem;                    // overlay: [64][33] u32 keys
  float* lpart = (float*)(smem + 8448);         // [4][64]
  float* qmS   = (float*)(smem + 9472);         // [64]
  float* MSs   = (float*)(smem + 9728);         // [64]
  float* linvS = (float*)(smem + 9984);         // [64]
  int*   flg   = (int*)(smem + 36864);          // [0]=pooled [1]=mw [2]=gm [3]=kmax2
#define PHB(b) (pbase + (b) * 9216)             // hi plane of buf b (u16 units)
#define PLB(b) (pbase + (b) * 9216 + 4608)      // lo plane

  const float* qg = q + ((size_t)bh * L + (size_t)iq * 64) * D;
  const u16* kh = khi_g + (size_t)bh * (L * D);
  const u16* kl = klo_g + (size_t)bh * (L * D);
  const u16* vh = vthi_g + (size_t)bh * (L * D);
  const u16* vl = vtlo_g + (size_t)bh * (L * D);

  // ---- Q B-frags: lane holds Q[qrow=16nt+m16][d = ks*32 + quad*8 + e] ----
  s16x8 qhf[4][2], qlf[4][2];
#pragma unroll
  for (int nt = 0; nt < 4; ++nt)
#pragma unroll
    for (int ks = 0; ks < 2; ++ks) {
      const float* p0 = qg + (size_t)(16 * nt + m16) * 64 + ks * 32 + quad * 8;
      float4 a = *(const float4*)p0;
      float4 b2 = *(const float4*)(p0 + 4);
      u32x2 ha, la, hb, lb;
      split4(a, ha, la); split4(b2, hb, lb);
      FragU fh, fl;
      fh.u[0] = ha[0]; fh.u[1] = ha[1]; fh.u[2] = hb[0]; fh.u[3] = hb[1];
      fl.u[0] = la[0]; fl.u[1] = la[1]; fl.u[2] = lb[0]; fl.u[3] = lb[1];
      qhf[nt][ks] = fh.v; qlf[nt][ks] = fl.v;
    }
  for (int e = t; e < 64 * 33; e += 256) rbm[e] = 0x7F800000u;

  // ---- phase 1: qm (w0), kmax2 (w1) ----
  if (w == 0) {
    float s = 0.f;
    for (int r = 0; r < 64; ++r) s += qg[r * 64 + lane];
    qmS[lane] = s * (1.f / 64.f);
  }
  if (w == 1) {
    float m = (lane < 32) ? kbmax[bh * 32 + lane] : 0.f;
    for (int off = 16; off; off >>= 1) m = fmaxf(m, __shfl_xor(m, off, 32));
    if (lane == 0) ((float*)flg)[3] = m;
  }
  __syncthreads();

  // ---- phase 2: CDF keep (w0); pooled cos + M (w1) ----
  bool keepj = false;
  if (w == 0 && lane < 32) {
    int j = lane;
    const float* ksp = ksum + (size_t)bh * NB * 64 + j * 64;
    float sv = 0.f;
    for (int d = 0; d < 64; ++d) sv += qmS[d] * ksp[d];
    sv *= (1.f / 64.f) * 0.125f;
    float mx = sv;
    for (int off = 16; off; off >>= 1) mx = fmaxf(mx, __shfl_xor(mx, off, 32));
    float p = expf(sv - mx);
    float sum = p;
    for (int off = 16; off; off >>= 1) sum += __shfl_xor(sum, off, 32);
    p /= sum;
    float excl = 0.f;
    for (int u = 0; u < 32; ++u) {
      float pu = __shfl(p, u, 32);
      if ((pu > p) || (pu == p && u < j)) excl += pu;
    }
    keepj = excl < cdfthreshd[h];
  }
  if (w == 1) {
    int r = lane;
    float kmax2 = ((float*)flg)[3];
    float dot = 0.f, qn2 = 0.f, qmn2 = 0.f;
    for (int d = 0; d < 64; ++d) {
      float a = qg[r * 64 + d], b2 = qmS[d];
      dot += a * b2; qn2 += a * a; qmn2 += b2 * b2;
    }
    float cs = dot / (sqrtf(qn2) * sqrtf(qmn2) + 1e-6f);
    float su = cs;
    for (int off = 32; off; off >>= 1) su += __shfl_xor(su, off);
    if (lane == 0) flg[0] = (su * (1.f / 64.f)) > simthreshd1[h];
    MSs[r] = sqrtf(qn2 * kmax2) * 0.125f;  // M_r >= |s| (Cauchy-Schwarz)
  }
  __syncthreads();
  if (w == 0 && lane < 32) {
    bool bit = keepj || !flg[0] || (lane == 0);
    unsigned long long bal = __ballot(bit);
    if (lane == 0) flg[1] = (int)(u32)bal;
  }
  __syncthreads();
  u32 mw = (u32)flg[1];

  float Mq[4];
#pragma unroll
  for (int nt = 0; nt < 4; ++nt) Mq[nt] = MSs[16 * nt + m16];

  // ---- Pass A: wave w owns K-rows 16w..16w+15 of each kept block ----
  float lp[4] = {0.f, 0.f, 0.f, 0.f};
  {
    u32 rm = mw;
    while (rm) {
      int j = (int)__builtin_ctz(rm); rm &= rm - 1;
      s16x8 ka[2][2];
      const u16* kr0 = kh + (size_t)(j * 64 + 16 * w + m16) * 64 + quad * 8;
      const u16* kl0 = kl + (size_t)(j * 64 + 16 * w + m16) * 64 + quad * 8;
#pragma unroll
      for (int ks = 0; ks < 2; ++ks) {
        ka[ks][0] = *(const s16x8*)(kr0 + ks * 32);
        ka[ks][1] = *(const s16x8*)(kl0 + ks * 32);
      }
      f32x4 acc[4];
#pragma unroll
      for (int nt = 0; nt < 4; ++nt) acc[nt] = (f32x4){0.f, 0.f, 0.f, 0.f};
      __builtin_amdgcn_s_setprio(1);
#pragma unroll
      for (int ks = 0; ks < 2; ++ks)
#pragma unroll
        for (int nt = 0; nt < 4; ++nt) {
          acc[nt] = __builtin_amdgcn_mfma_f32_16x16x32_bf16(ka[ks][0], qhf[nt][ks], acc[nt], 0, 0, 0);
          acc[nt] = __builtin_amdgcn_mfma_f32_16x16x32_bf16(ka[ks][1], qhf[nt][ks], acc[nt], 0, 0, 0);
          acc[nt] = __builtin_amdgcn_mfma_f32_16x16x32_bf16(ka[ks][0], qlf[nt][ks], acc[nt], 0, 0, 0);
        }
      __builtin_amdgcn_s_setprio(0);
#pragma unroll
      for (int nt = 0; nt < 4; ++nt) {
        float vmax = -1e30f;
#pragma unroll
        for (int reg = 0; reg < 4; ++reg) {
          float s = acc[nt][reg] * 0.125f - Mq[nt];
          lp[nt] += __expf(s);
          vmax = fmaxf(vmax, s);
        }
        vmax = fmaxf(vmax, __shfl_xor(vmax, 16));
        vmax = fmaxf(vmax, __shfl_xor(vmax, 32));
        if (quad == 0)
          atomicMin(rbm + (16 * nt + m16) * 33 + j, __float_as_uint(fmaxf(-vmax, 0.f)));
      }
    }
  }
#pragma unroll
  for (int nt = 0; nt < 4; ++nt) {
    float s = lp[nt];
    s += __shfl_xor(s, 16); s += __shfl_xor(s, 32);
    if (quad == 0) lpart[w * 64 + 16 * nt + m16] = s;
  }
  __syncthreads();
  if (t < 64) linvS[t] = 1.f / (lpart[t] + lpart[64 + t] + lpart[128 + t] + lpart[192 + t]);
  __syncthreads();

  // ---- PV gate (w0) ----
  if (w == 0 && lane < 32) {
    bool keep = (mw >> lane) & 1u;
    if (keep && lane != 0) {
      float thr = pvthreshd[h] * 1e-3f;
      float mp = 0.f;
      for (int r = 0; r < 64; ++r) {
        float key = __uint_as_float(rbm[r * 33 + lane]);
        mp = fmaxf(mp, __expf(-key) * linvS[r]);
      }
      keep = mp >= thr;
    }
    unsigned long long bal = __ballot(keep);
    if (lane == 0) flg[2] = (int)(u32)bal;
  }
  __syncthreads();
  u32 gm = (u32)flg[2];

  float linq[4];
#pragma unroll
  for (int nt = 0; nt < 4; ++nt) linq[nt] = linvS[16 * nt + m16];
  __syncthreads();   // all linv/rbm reads done before P-writes overwrite overlay

  // ---- Pass B: double-buffered P, one barrier per j ----
  f32x4 oacc[4];
#pragma unroll
  for (int nt = 0; nt < 4; ++nt) oacc[nt] = (f32x4){0.f, 0.f, 0.f, 0.f};
  {
    u32 rg = gm;
    int buf = 0;
    while (rg) {
      int j = (int)__builtin_ctz(rg); rg &= rg - 1;
      // S: wave's 16 K-rows x 64 q
      s16x8 ka[2][2];
      const u16* kr0 = kh + (size_t)(j * 64 + 16 * w + m16) * 64 + quad * 8;
      const u16* kl0 = kl + (size_t)(j * 64 + 16 * w + m16) * 64 + quad * 8;
#pragma unroll
      for (int ks = 0; ks < 2; ++ks) {
        ka[ks][0] = *(const s16x8*)(kr0 + ks * 32);
        ka[ks][1] = *(const s16x8*)(kl0 + ks * 32);
      }
      f32x4 acc[4];
#pragma unroll
      for (int nt = 0; nt < 4; ++nt) acc[nt] = (f32x4){0.f, 0.f, 0.f, 0.f};
      __builtin_amdgcn_s_setprio(1);
#pragma unroll
      for (int ks = 0; ks < 2; ++ks)
#pragma unroll
        for (int nt = 0; nt < 4; ++nt) {
          acc[nt] = __builtin_amdgcn_mfma_f32_16x16x32_bf16(ka[ks][0], qhf[nt][ks], acc[nt], 0, 0, 0);
          acc[nt] = __builtin_amdgcn_mfma_f32_16x16x32_bf16(ka[ks][1], qhf[nt][ks], acc[nt], 0, 0, 0);
          acc[nt] = __builtin_amdgcn_mfma_f32_16x16x32_bf16(ka[ks][0], qlf[nt][ks], acc[nt], 0, 0, 0);
        }
      __builtin_amdgcn_s_setprio(0);
      // P = exp(S-M)*linv -> split -> P[buf][qrow][kcol 16w+4quad..]
      u16* ph = PHB(buf);
      u16* pl = PLB(buf);
#pragma unroll
      for (int nt = 0; nt < 4; ++nt) {
        float4 pv;
        pv.x = __expf(acc[nt][0] * 0.125f - Mq[nt]) * linq[nt];
        pv.y = __expf(acc[nt][1] * 0.125f - Mq[nt]) * linq[nt];
        pv.z = __expf(acc[nt][2] * 0.125f - Mq[nt]) * linq[nt];
        pv.w = __expf(acc[nt][3] * 0.125f - Mq[nt]) * linq[nt];
        u32x2 hi, lo; split4(pv, hi, lo);
        int off = (16 * nt + m16) * PTS + 16 * w + 4 * quad;
        *(u32x2*)(ph + off) = hi;
        *(u32x2*)(pl + off) = lo;
      }
      __syncthreads();   // P[buf] complete; prior-j reads finished (double buffer)
      // PV: A = V^T rows 16w..16w+15, B = P frags from LDS
      s16x8 va[2][2];
      const u16* vr0 = vh + (size_t)(16 * w + m16) * L + j * 64 + quad * 8;
      const u16* vl0 = vl + (size_t)(16 * w + m16) * L + j * 64 + quad * 8;
#pragma unroll
      for (int ks = 0; ks < 2; ++ks) {
        va[ks][0] = *(const s16x8*)(vr0 + ks * 32);
        va[ks][1] = *(const s16x8*)(vl0 + ks * 32);
      }
#pragma unroll
      for (int ks = 0; ks < 2; ++ks)
#pragma unroll
        for (int nt = 0; nt < 4; ++nt) {
          s16x8 pbh = *(const s16x8*)(ph + (16 * nt + m16) * PTS + ks * 32 + quad * 8);
          s16x8 pbl = *(const s16x8*)(pl + (16 * nt + m16) * PTS + ks * 32 + quad * 8);
          __builtin_amdgcn_s_setprio(1);
          oacc[nt] = __builtin_amdgcn_mfma_f32_16x16x32_bf16(va[ks][0], pbh, oacc[nt], 0, 0, 0);
          oacc[nt] = __builtin_amdgcn_mfma_f32_16x16x32_bf16(va[ks][1], pbh, oacc[nt], 0, 0, 0);
          oacc[nt] = __builtin_amdgcn_mfma_f32_16x16x32_bf16(va[ks][0], pbl, oacc[nt], 0, 0, 0);
          __builtin_amdgcn_s_setprio(0);
        }
      buf ^= 1;
    }
  }

  // ---- store O: lane -> qrow = 16nt+m16, d = 16w+4quad (f32x4 over reg) ----
  float* ob = out + ((size_t)bh * L + (size_t)iq * 64) * D;
#pragma unroll
  for (int nt = 0; nt < 4; ++nt)
    *(f32x4*)(ob + (size_t)(16 * nt + m16) * 64 + 16 * w + 4 * quad) = oacc[nt];
}

// ---------------------------------------------------------------------------
extern "C" void kernel_launch(void* const* d_in, const int* in_sizes, int n_in,
                              void* d_out, int out_size, void* d_ws, size_t ws_size,
                              hipStream_t stream) {
  (void)in_sizes; (void)n_in; (void)out_size; (void)ws_size;
  const float* q   = (const float*)d_in[0];
  const float* k   = (const float*)d_in[1];
  const float* v   = (const float*)d_in[2];
  const float* cdf = (const float*)d_in[3];
  const float* sim = (const float*)d_in[4];
  const float* pvt = (const float*)d_in[5];
  float* out = (float*)d_out;

  uint8_t* w8 = (uint8_t*)d_ws;
  float* ksum  = (float*)w8;                          // 1024*64 f (256 KB)
  float* kbmax = (float*)(w8 + 262144);               // 1024 f (4 KB)
  u16* khi_g  = (u16*)(w8 + 266240);                  // 4 planes x 8 MB
  u16* klo_g  = khi_g + (size_t)B * H * L * D;
  u16* vthi_g = klo_g + (size_t)B * H * L * D;
  u16* vtlo_g = vthi_g + (size_t)B * H * L * D;

  k_prep<<<B * H * NB, 256, 0, stream>>>(k, v, ksum, khi_g, klo_g, vthi_g, vtlo_g, kbmax);
  k_attn<<<B * H * NB, 256, 0, stream>>>(q, ksum, khi_g, klo_g, vthi_g, vtlo_g,
                                         cdf, sim, pvt, kbmax, out);
}

// Round 4
// 231.394 us; speedup vs baseline: 1.8460x; 1.0334x over previous
//
#include <hip/hip_runtime.h>
#include <hip/hip_bf16.h>
#include <math.h>
#include <stdint.h>

#define B 2
#define H 16
#define L 2048
#define D 64
#define NB 32
#define PTS 72            // row stride in u16 (144 B) for P and Q-lo tiles

typedef unsigned short u16;
typedef unsigned int u32;
typedef __attribute__((ext_vector_type(2))) unsigned int u32x2;
typedef __attribute__((ext_vector_type(4))) unsigned int u32x4;
typedef __attribute__((ext_vector_type(8))) short s16x8;
typedef __attribute__((ext_vector_type(4))) float f32x4;

union FragU { s16x8 v; u32 u[4]; };

__device__ __forceinline__ u32 pkbf(float a, float b) {
  __hip_bfloat162 h = __float22bfloat162_rn(make_float2(a, b));  // v_cvt_pk_bf16_f32
  union { __hip_bfloat162 h; u32 u; } cv; cv.h = h; return cv.u;
}
__device__ __forceinline__ float bf2f(u32 u16bits) {
  union { u32 u; float f; } c; c.u = u16bits << 16; return c.f;
}
// split float4 -> packed hi (u32x2) + lo (u32x2), RNE both levels
__device__ __forceinline__ void split4(float4 p, u32x2& hi, u32x2& lo) {
  u32 h01 = pkbf(p.x, p.y), h23 = pkbf(p.z, p.w);
  float rx = p.x - bf2f(h01 & 0xffffu);
  float ry = p.y - bf2f(h01 >> 16);
  float rz = p.z - bf2f(h23 & 0xffffu);
  float rw = p.w - bf2f(h23 >> 16);
  hi = (u32x2){h01, h23};
  lo = (u32x2){pkbf(rx, ry), pkbf(rz, rw)};
}

// ---------------------------------------------------------------------------
// k_prep: single pass over K (split + column sums fused), V transpose split.
// 16 B stores on all four bf16 planes. Per-(bh,j) max ||k_row||^2.
// ---------------------------------------------------------------------------
__global__ __launch_bounds__(256) void k_prep(const float* __restrict__ k,
                                              const float* __restrict__ v,
                                              float* __restrict__ ksum,
                                              u16* __restrict__ khi_g,
                                              u16* __restrict__ klo_g,
                                              u16* __restrict__ vthi_g,
                                              u16* __restrict__ vtlo_g,
                                              float* __restrict__ kbmax) {
  int blk = blockIdx.x, bh = blk >> 5, j = blk & 31, t = threadIdx.x;
  int lane = t & 63, w = t >> 6;
  __shared__ float vt[64 * 65];
  __shared__ float pk_[4][64];
  __shared__ unsigned bmaxS;
  if (t == 0) bmaxS = 0u;
  size_t base = (size_t)blk * 4096;

  int r0 = t >> 3;          // 0..31
  int c8 = (t & 7) * 8;     // 0..56
  float cs[8] = {0.f, 0.f, 0.f, 0.f, 0.f, 0.f, 0.f, 0.f};
  float rmax = 0.f;
#pragma unroll
  for (int it = 0; it < 2; ++it) {
    int r = r0 + 32 * it;
    const float* kp = k + base + r * 64 + c8;
    float4 f0 = *(const float4*)kp;
    float4 f1 = *(const float4*)(kp + 4);
    u32x2 h0, l0, h1, l1;
    split4(f0, h0, l0); split4(f1, h1, l1);
    *(u32x4*)(khi_g + base + r * 64 + c8) = (u32x4){h0[0], h0[1], h1[0], h1[1]};
    *(u32x4*)(klo_g + base + r * 64 + c8) = (u32x4){l0[0], l0[1], l1[0], l1[1]};
    cs[0] += f0.x; cs[1] += f0.y; cs[2] += f0.z; cs[3] += f0.w;
    cs[4] += f1.x; cs[5] += f1.y; cs[6] += f1.z; cs[7] += f1.w;
    float ssq = f0.x*f0.x + f0.y*f0.y + f0.z*f0.z + f0.w*f0.w
              + f1.x*f1.x + f1.y*f1.y + f1.z*f1.z + f1.w*f1.w;
    ssq += __shfl_xor(ssq, 1); ssq += __shfl_xor(ssq, 2); ssq += __shfl_xor(ssq, 4);
    if ((t & 7) == 0) rmax = fmaxf(rmax, ssq);
    const float* vp = v + base + r * 64 + c8;
    float4 g0 = *(const float4*)vp;
    float4 g1 = *(const float4*)(vp + 4);
    vt[(c8 + 0) * 65 + r] = g0.x;
    vt[(c8 + 1) * 65 + r] = g0.y;
    vt[(c8 + 2) * 65 + r] = g0.z;
    vt[(c8 + 3) * 65 + r] = g0.w;
    vt[(c8 + 4) * 65 + r] = g1.x;
    vt[(c8 + 5) * 65 + r] = g1.y;
    vt[(c8 + 6) * 65 + r] = g1.z;
    vt[(c8 + 7) * 65 + r] = g1.w;
  }
  if ((t & 7) == 0) atomicMax(&bmaxS, __float_as_uint(rmax));
  // column-sum reduce over r-groups: xor 8/16/32 keep lane&7 (the column group)
#pragma unroll
  for (int i = 0; i < 8; ++i) {
    cs[i] += __shfl_xor(cs[i], 8);
    cs[i] += __shfl_xor(cs[i], 16);
    cs[i] += __shfl_xor(cs[i], 32);
  }
  if (lane < 8) {
    *(float4*)&pk_[w][lane * 8]     = (float4){cs[0], cs[1], cs[2], cs[3]};
    *(float4*)&pk_[w][lane * 8 + 4] = (float4){cs[4], cs[5], cs[6], cs[7]};
  }
  __syncthreads();
  if (t < 64) ksum[(size_t)blk * 64 + t] = pk_[0][t] + pk_[1][t] + pk_[2][t] + pk_[3][t];
  if (t == 0) kbmax[blk] = __uint_as_float(bmaxS);
#pragma unroll
  for (int it = 0; it < 2; ++it) {
    int idx = t + 256 * it, d = idx >> 3, s8 = (idx & 7) * 8;
    const float* vr = &vt[d * 65 + s8];
    float4 f0 = {vr[0], vr[1], vr[2], vr[3]};
    float4 f1 = {vr[4], vr[5], vr[6], vr[7]};
    u32x2 h0, l0, h1, l1;
    split4(f0, h0, l0); split4(f1, h1, l1);
    size_t o = (size_t)bh * 131072 + (size_t)d * 2048 + j * 64 + s8;
    *(u32x4*)(vthi_g + o) = (u32x4){h0[0], h0[1], h1[0], h1[1]};
    *(u32x4*)(vtlo_g + o) = (u32x4){l0[0], l0[1], l1[0], l1[1]};
  }
}

// ---------------------------------------------------------------------------
// k_attn: ONE q-block per WG, waves split K-rows (no load duplication).
// Spill-free at 4 WGs/CU: Q-lo plane lives in LDS ([64][72] u16, 2-way-free
// banks), Q-hi in registers (32 VGPR). Single-buffered P + 2 barriers/j.
// K prefetched across j in both passes; V issued one barrier early.
// LDS map (bytes), total 27680 -> 4 WGs/CU (VGPR-capped at 128):
//   P hi 0..9216 | P lo 9216..18432   (overlay, dead before Pass B:
//     rbm u32[64*33] @0 (8448), lpart[4][64] @8448, qm[64] @9472,
//     MS[64] @9728, linv[64] @9984)
//   Qlo [64][72] u16 @18432..27648 (live whole kernel)
//   flg @27648
// ---------------------------------------------------------------------------
__global__ __launch_bounds__(256, 4) void k_attn(
    const float* __restrict__ q,
    const float* __restrict__ ksum,
    const u16* __restrict__ khi_g, const u16* __restrict__ klo_g,
    const u16* __restrict__ vthi_g, const u16* __restrict__ vtlo_g,
    const float* __restrict__ cdfthreshd, const float* __restrict__ simthreshd1,
    const float* __restrict__ pvthreshd, const float* __restrict__ kbmax,
    float* __restrict__ out) {
  int blk0 = blockIdx.x;
  int blk = (blk0 & 7) * 128 + (blk0 >> 3);   // bijective: 1024 % 8 == 0
  int bh = blk >> 5, iq = blk & 31, h = bh & (H - 1);
  int t = threadIdx.x, lane = t & 63, w = t >> 6;
  int m16 = lane & 15, quad = lane >> 4;

  __shared__ __align__(16) uint8_t smem[27680];
  u16*   pbase = (u16*)smem;                    // P planes (u16 units)
  u32*   rbm   = (u32*)smem;                    // overlay: [64][33] u32 keys
  float* lpart = (float*)(smem + 8448);         // [4][64]
  float* qmS   = (float*)(smem + 9472);         // [64]
  float* MSs   = (float*)(smem + 9728);         // [64]
  float* linvS = (float*)(smem + 9984);         // [64]
  u16*   qlo   = (u16*)(smem + 18432);          // [64][72] u16
  int*   flg   = (int*)(smem + 27648);          // [0]=pooled [1]=mw [2]=gm [3]=kmax2
  u16* PH = pbase;                              // P hi plane
  u16* PL = pbase + 4608;                       // P lo plane

  const float* qg = q + ((size_t)bh * L + (size_t)iq * 64) * D;
  const u16* kh = khi_g + (size_t)bh * (L * D);
  const u16* kl = klo_g + (size_t)bh * (L * D);
  const u16* vh = vthi_g + (size_t)bh * (L * D);
  const u16* vl = vtlo_g + (size_t)bh * (L * D);

  // ---- Q B-frags: hi -> registers (32 VGPR), lo -> LDS tile ----
  s16x8 qhf[4][2];
#pragma unroll
  for (int nt = 0; nt < 4; ++nt)
#pragma unroll
    for (int ks = 0; ks < 2; ++ks) {
      const float* p0 = qg + (size_t)(16 * nt + m16) * 64 + ks * 32 + quad * 8;
      float4 a = *(const float4*)p0;
      float4 b2 = *(const float4*)(p0 + 4);
      u32x2 ha, la, hb, lb;
      split4(a, ha, la); split4(b2, hb, lb);
      FragU fh;
      fh.u[0] = ha[0]; fh.u[1] = ha[1]; fh.u[2] = hb[0]; fh.u[3] = hb[1];
      qhf[nt][ks] = fh.v;
      *(u32x4*)(qlo + (16 * nt + m16) * PTS + ks * 32 + quad * 8) =
          (u32x4){la[0], la[1], lb[0], lb[1]};
    }
  for (int e = t; e < 64 * 33; e += 256) rbm[e] = 0x7F800000u;

  // ---- phase 1: qm (w0), kmax2 (w1) ----
  if (w == 0) {
    float s = 0.f;
    for (int r = 0; r < 64; ++r) s += qg[r * 64 + lane];
    qmS[lane] = s * (1.f / 64.f);
  }
  if (w == 1) {
    float m = (lane < 32) ? kbmax[bh * 32 + lane] : 0.f;
    for (int off = 16; off; off >>= 1) m = fmaxf(m, __shfl_xor(m, off, 32));
    if (lane == 0) ((float*)flg)[3] = m;
  }
  __syncthreads();

  // ---- phase 2: CDF keep (w0); pooled cos + M (w1) ----
  bool keepj = false;
  if (w == 0 && lane < 32) {
    int j = lane;
    const float* ksp = ksum + (size_t)bh * NB * 64 + j * 64;
    float sv = 0.f;
    for (int d = 0; d < 64; ++d) sv += qmS[d] * ksp[d];
    sv *= (1.f / 64.f) * 0.125f;
    float mx = sv;
    for (int off = 16; off; off >>= 1) mx = fmaxf(mx, __shfl_xor(mx, off, 32));
    float p = expf(sv - mx);
    float sum = p;
    for (int off = 16; off; off >>= 1) sum += __shfl_xor(sum, off, 32);
    p /= sum;
    float excl = 0.f;
    for (int u = 0; u < 32; ++u) {
      float pu = __shfl(p, u, 32);
      if ((pu > p) || (pu == p && u < j)) excl += pu;
    }
    keepj = excl < cdfthreshd[h];
  }
  if (w == 1) {
    int r = lane;
    float kmax2 = ((float*)flg)[3];
    float dot = 0.f, qn2 = 0.f, qmn2 = 0.f;
    for (int d = 0; d < 64; ++d) {
      float a = qg[r * 64 + d], b2 = qmS[d];
      dot += a * b2; qn2 += a * a; qmn2 += b2 * b2;
    }
    float cs = dot / (sqrtf(qn2) * sqrtf(qmn2) + 1e-6f);
    float su = cs;
    for (int off = 32; off; off >>= 1) su += __shfl_xor(su, off);
    if (lane == 0) flg[0] = (su * (1.f / 64.f)) > simthreshd1[h];
    MSs[r] = sqrtf(qn2 * kmax2) * 0.125f;  // M_r >= |s| (Cauchy-Schwarz)
  }
  __syncthreads();
  if (w == 0 && lane < 32) {
    bool bit = keepj || !flg[0] || (lane == 0);
    unsigned long long bal = __ballot(bit);
    if (lane == 0) flg[1] = (int)(u32)bal;
  }
  __syncthreads();
  u32 mw = (u32)flg[1];

  float Mq[4];
#pragma unroll
  for (int nt = 0; nt < 4; ++nt) Mq[nt] = MSs[16 * nt + m16];

  // ---- Pass A: wave w owns K-rows 16w..16w+15; K prefetched across j ----
  float lp[4] = {0.f, 0.f, 0.f, 0.f};
  {
    u32 rm = mw;
    int j = (int)__builtin_ctz(rm); rm &= rm - 1;
    s16x8 ka0[2], ka1[2];
    {
      const u16* kr0 = kh + (size_t)(j * 64 + 16 * w + m16) * 64 + quad * 8;
      const u16* kl0 = kl + (size_t)(j * 64 + 16 * w + m16) * 64 + quad * 8;
#pragma unroll
      for (int ks = 0; ks < 2; ++ks) {
        ka0[ks] = *(const s16x8*)(kr0 + ks * 32);
        ka1[ks] = *(const s16x8*)(kl0 + ks * 32);
      }
    }
    for (;;) {
      f32x4 acc[4];
#pragma unroll
      for (int nt = 0; nt < 4; ++nt) acc[nt] = (f32x4){0.f, 0.f, 0.f, 0.f};
#pragma unroll
      for (int ks = 0; ks < 2; ++ks) {
        s16x8 ql_[4];
#pragma unroll
        for (int nt = 0; nt < 4; ++nt)
          ql_[nt] = *(const s16x8*)(qlo + (16 * nt + m16) * PTS + ks * 32 + quad * 8);
        __builtin_amdgcn_s_setprio(1);
#pragma unroll
        for (int nt = 0; nt < 4; ++nt) {
          acc[nt] = __builtin_amdgcn_mfma_f32_16x16x32_bf16(ka0[ks], qhf[nt][ks], acc[nt], 0, 0, 0);
          acc[nt] = __builtin_amdgcn_mfma_f32_16x16x32_bf16(ka1[ks], qhf[nt][ks], acc[nt], 0, 0, 0);
          acc[nt] = __builtin_amdgcn_mfma_f32_16x16x32_bf16(ka0[ks], ql_[nt], acc[nt], 0, 0, 0);
        }
        __builtin_amdgcn_s_setprio(0);
      }
      // prefetch next-j K while exp/reductions run
      int nj = -1;
      s16x8 kn0[2], kn1[2];
      if (rm) {
        nj = (int)__builtin_ctz(rm); rm &= rm - 1;
        const u16* nr = kh + (size_t)(nj * 64 + 16 * w + m16) * 64 + quad * 8;
        const u16* nl = kl + (size_t)(nj * 64 + 16 * w + m16) * 64 + quad * 8;
#pragma unroll
        for (int ks = 0; ks < 2; ++ks) {
          kn0[ks] = *(const s16x8*)(nr + ks * 32);
          kn1[ks] = *(const s16x8*)(nl + ks * 32);
        }
      }
#pragma unroll
      for (int nt = 0; nt < 4; ++nt) {
        float vmax = -1e30f;
#pragma unroll
        for (int reg = 0; reg < 4; ++reg) {
          float s = acc[nt][reg] * 0.125f - Mq[nt];
          lp[nt] += __expf(s);
          vmax = fmaxf(vmax, s);
        }
        vmax = fmaxf(vmax, __shfl_xor(vmax, 16));
        vmax = fmaxf(vmax, __shfl_xor(vmax, 32));
        if (quad == 0)
          atomicMin(rbm + (16 * nt + m16) * 33 + j, __float_as_uint(fmaxf(-vmax, 0.f)));
      }
      if (nj < 0) break;
#pragma unroll
      for (int ks = 0; ks < 2; ++ks) { ka0[ks] = kn0[ks]; ka1[ks] = kn1[ks]; }
      j = nj;
    }
  }
#pragma unroll
  for (int nt = 0; nt < 4; ++nt) {
    float s = lp[nt];
    s += __shfl_xor(s, 16); s += __shfl_xor(s, 32);
    if (quad == 0) lpart[w * 64 + 16 * nt + m16] = s;
  }
  __syncthreads();
  if (t < 64) linvS[t] = 1.f / (lpart[t] + lpart[64 + t] + lpart[128 + t] + lpart[192 + t]);
  __syncthreads();

  // ---- PV gate (w0) ----
  if (w == 0 && lane < 32) {
    bool keep = (mw >> lane) & 1u;
    if (keep && lane != 0) {
      float thr = pvthreshd[h] * 1e-3f;
      float mp = 0.f;
      for (int r = 0; r < 64; ++r) {
        float key = __uint_as_float(rbm[r * 33 + lane]);
        mp = fmaxf(mp, __expf(-key) * linvS[r]);
      }
      keep = mp >= thr;
    }
    unsigned long long bal = __ballot(keep);
    if (lane == 0) flg[2] = (int)(u32)bal;
  }
  __syncthreads();
  u32 gm = (u32)flg[2];

  float linq[4];
#pragma unroll
  for (int nt = 0; nt < 4; ++nt) linq[nt] = linvS[16 * nt + m16];

  // ---- Pass B: single-buffer P, 2 barriers/j, K prefetch, early V ----
  f32x4 oacc[4];
#pragma unroll
  for (int nt = 0; nt < 4; ++nt) oacc[nt] = (f32x4){0.f, 0.f, 0.f, 0.f};
  {
    u32 rg = gm;
    int j = (int)__builtin_ctz(rg); rg &= rg - 1;   // gm always has sink bit 0
    s16x8 ka0[2], ka1[2];
    {
      const u16* kr0 = kh + (size_t)(j * 64 + 16 * w + m16) * 64 + quad * 8;
      const u16* kl0 = kl + (size_t)(j * 64 + 16 * w + m16) * 64 + quad * 8;
#pragma unroll
      for (int ks = 0; ks < 2; ++ks) {
        ka0[ks] = *(const s16x8*)(kr0 + ks * 32);
        ka1[ks] = *(const s16x8*)(kl0 + ks * 32);
      }
    }
    for (;;) {
      // S: wave's 16 K-rows x 64 q
      f32x4 acc[4];
#pragma unroll
      for (int nt = 0; nt < 4; ++nt) acc[nt] = (f32x4){0.f, 0.f, 0.f, 0.f};
#pragma unroll
      for (int ks = 0; ks < 2; ++ks) {
        s16x8 ql_[4];
#pragma unroll
        for (int nt = 0; nt < 4; ++nt)
          ql_[nt] = *(const s16x8*)(qlo + (16 * nt + m16) * PTS + ks * 32 + quad * 8);
        __builtin_amdgcn_s_setprio(1);
#pragma unroll
        for (int nt = 0; nt < 4; ++nt) {
          acc[nt] = __builtin_amdgcn_mfma_f32_16x16x32_bf16(ka0[ks], qhf[nt][ks], acc[nt], 0, 0, 0);
          acc[nt] = __builtin_amdgcn_mfma_f32_16x16x32_bf16(ka1[ks], qhf[nt][ks], acc[nt], 0, 0, 0);
          acc[nt] = __builtin_amdgcn_mfma_f32_16x16x32_bf16(ka0[ks], ql_[nt], acc[nt], 0, 0, 0);
        }
        __builtin_amdgcn_s_setprio(0);
      }
      // prefetch next-j K (covered by exp + P-write + barrier + PV)
      int nj = -1;
      s16x8 kn0[2], kn1[2];
      if (rg) {
        nj = (int)__builtin_ctz(rg); rg &= rg - 1;
        const u16* nr = kh + (size_t)(nj * 64 + 16 * w + m16) * 64 + quad * 8;
        const u16* nl = kl + (size_t)(nj * 64 + 16 * w + m16) * 64 + quad * 8;
#pragma unroll
        for (int ks = 0; ks < 2; ++ks) {
          kn0[ks] = *(const s16x8*)(nr + ks * 32);
          kn1[ks] = *(const s16x8*)(nl + ks * 32);
        }
      }
      __syncthreads();   // prior PV reads of P complete; safe to overwrite
      // P = exp(S-M)*linv -> split -> P[qrow][kcol 16w+4quad..]
#pragma unroll
      for (int nt = 0; nt < 4; ++nt) {
        float4 pv;
        pv.x = __expf(acc[nt][0] * 0.125f - Mq[nt]) * linq[nt];
        pv.y = __expf(acc[nt][1] * 0.125f - Mq[nt]) * linq[nt];
        pv.z = __expf(acc[nt][2] * 0.125f - Mq[nt]) * linq[nt];
        pv.w = __expf(acc[nt][3] * 0.125f - Mq[nt]) * linq[nt];
        u32x2 hi, lo; split4(pv, hi, lo);
        int off = (16 * nt + m16) * PTS + 16 * w + 4 * quad;
        *(u32x2*)(PH + off) = hi;
        *(u32x2*)(PL + off) = lo;
      }
      // V^T A-frags for current j (consumed after the barrier)
      s16x8 va0[2], va1[2];
      {
        const u16* vr0 = vh + (size_t)(16 * w + m16) * L + j * 64 + quad * 8;
        const u16* vl0 = vl + (size_t)(16 * w + m16) * L + j * 64 + quad * 8;
#pragma unroll
        for (int ks = 0; ks < 2; ++ks) {
          va0[ks] = *(const s16x8*)(vr0 + ks * 32);
          va1[ks] = *(const s16x8*)(vl0 + ks * 32);
        }
      }
      __syncthreads();   // P complete
      // PV: A = V^T rows 16w..16w+15, B = P frags from LDS
#pragma unroll
      for (int ks = 0; ks < 2; ++ks)
#pragma unroll
        for (int nt = 0; nt < 4; ++nt) {
          s16x8 pbh = *(const s16x8*)(PH + (16 * nt + m16) * PTS + ks * 32 + quad * 8);
          s16x8 pbl = *(const s16x8*)(PL + (16 * nt + m16) * PTS + ks * 32 + quad * 8);
          __builtin_amdgcn_s_setprio(1);
          oacc[nt] = __builtin_amdgcn_mfma_f32_16x16x32_bf16(va0[ks], pbh, oacc[nt], 0, 0, 0);
          oacc[nt] = __builtin_amdgcn_mfma_f32_16x16x32_bf16(va1[ks], pbh, oacc[nt], 0, 0, 0);
          oacc[nt] = __builtin_amdgcn_mfma_f32_16x16x32_bf16(va0[ks], pbl, oacc[nt], 0, 0, 0);
          __builtin_amdgcn_s_setprio(0);
        }
      if (nj < 0) break;
#pragma unroll
      for (int ks = 0; ks < 2; ++ks) { ka0[ks] = kn0[ks]; ka1[ks] = kn1[ks]; }
      j = nj;
    }
  }

  // ---- store O: lane -> qrow = 16nt+m16, d = 16w+4quad (f32x4 over reg) ----
  float* ob = out + ((size_t)bh * L + (size_t)iq * 64) * D;
#pragma unroll
  for (int nt = 0; nt < 4; ++nt)
    *(f32x4*)(ob + (size_t)(16 * nt + m16) * 64 + 16 * w + 4 * quad) = oacc[nt];
}

// ---------------------------------------------------------------------------
extern "C" void kernel_launch(void* const* d_in, const int* in_sizes, int n_in,
                              void* d_out, int out_size, void* d_ws, size_t ws_size,
                              hipStream_t stream) {
  (void)in_sizes; (void)n_in; (void)out_size; (void)ws_size;
  const float* q   = (const float*)d_in[0];
  const float* k   = (const float*)d_in[1];
  const float* v   = (const float*)d_in[2];
  const float* cdf = (const float*)d_in[3];
  const float* sim = (const float*)d_in[4];
  const float* pvt = (const float*)d_in[5];
  float* out = (float*)d_out;

  uint8_t* w8 = (uint8_t*)d_ws;
  float* ksum  = (float*)w8;                          // 1024*64 f (256 KB)
  float* kbmax = (float*)(w8 + 262144);               // 1024 f (4 KB)
  u16* khi_g  = (u16*)(w8 + 266240);                  // 4 planes x 8 MB
  u16* klo_g  = khi_g + (size_t)B * H * L * D;
  u16* vthi_g = klo_g + (size_t)B * H * L * D;
  u16* vtlo_g = vthi_g + (size_t)B * H * L * D;

  k_prep<<<B * H * NB, 256, 0, stream>>>(k, v, ksum, khi_g, klo_g, vthi_g, vtlo_g, kbmax);
  k_attn<<<B * H * NB, 256, 0, stream>>>(q, ksum, khi_g, klo_g, vthi_g, vtlo_g,
                                         cdf, sim, pvt, kbmax, out);
}

// Round 5
// 215.456 us; speedup vs baseline: 1.9825x; 1.0740x over previous
//
#include <hip/hip_runtime.h>
#include <hip/hip_bf16.h>
#include <math.h>
#include <stdint.h>

#define B 2
#define H 16
#define L 2048
#define D 64
#define NB 32

typedef unsigned short u16;
typedef unsigned int u32;
typedef __attribute__((ext_vector_type(2))) unsigned int u32x2;
typedef __attribute__((ext_vector_type(4))) unsigned int u32x4;
typedef __attribute__((ext_vector_type(8))) short s16x8;
typedef __attribute__((ext_vector_type(4))) float f32x4;

union FragU { s16x8 v; u32 u[4]; };

__device__ __forceinline__ u32 pkbf(float a, float b) {
  __hip_bfloat162 h = __float22bfloat162_rn(make_float2(a, b));  // v_cvt_pk_bf16_f32
  union { __hip_bfloat162 h; u32 u; } cv; cv.h = h; return cv.u;
}
__device__ __forceinline__ float bf2f(u32 u16bits) {
  union { u32 u; float f; } c; c.u = u16bits << 16; return c.f;
}
// split float4 -> packed hi (u32x2) + lo (u32x2), RNE both levels
__device__ __forceinline__ void split4(float4 p, u32x2& hi, u32x2& lo) {
  u32 h01 = pkbf(p.x, p.y), h23 = pkbf(p.z, p.w);
  float rx = p.x - bf2f(h01 & 0xffffu);
  float ry = p.y - bf2f(h01 >> 16);
  float rz = p.z - bf2f(h23 & 0xffffu);
  float rw = p.w - bf2f(h23 >> 16);
  hi = (u32x2){h01, h23};
  lo = (u32x2){pkbf(rx, ry), pkbf(rz, rw)};
}
// XOR-swizzled byte offset in a [64][128B] tile: 2 lanes/bank (free) for the
// fixed-col/varying-row ds_read_b128 pattern (guide §6 G4).
__device__ __forceinline__ int swz(int row, int colb) {
  return (row << 7) + (colb ^ ((row & 7) << 4));
}

// ---------------------------------------------------------------------------
// k_prep: single pass over K (split + column sums fused), V transpose split.
// 16 B stores on all four bf16 planes. Per-(bh,j) max ||k_row||^2.
// ---------------------------------------------------------------------------
__global__ __launch_bounds__(256) void k_prep(const float* __restrict__ k,
                                              const float* __restrict__ v,
                                              float* __restrict__ ksum,
                                              u16* __restrict__ khi_g,
                                              u16* __restrict__ klo_g,
                                              u16* __restrict__ vthi_g,
                                              u16* __restrict__ vtlo_g,
                                              float* __restrict__ kbmax) {
  int blk = blockIdx.x, bh = blk >> 5, j = blk & 31, t = threadIdx.x;
  int lane = t & 63, w = t >> 6;
  __shared__ float vt[64 * 65];
  __shared__ float pk_[4][64];
  __shared__ unsigned bmaxS;
  if (t == 0) bmaxS = 0u;
  size_t base = (size_t)blk * 4096;

  int r0 = t >> 3;          // 0..31
  int c8 = (t & 7) * 8;     // 0..56
  float cs[8] = {0.f, 0.f, 0.f, 0.f, 0.f, 0.f, 0.f, 0.f};
  float rmax = 0.f;
#pragma unroll
  for (int it = 0; it < 2; ++it) {
    int r = r0 + 32 * it;
    const float* kp = k + base + r * 64 + c8;
    float4 f0 = *(const float4*)kp;
    float4 f1 = *(const float4*)(kp + 4);
    u32x2 h0, l0, h1, l1;
    split4(f0, h0, l0); split4(f1, h1, l1);
    *(u32x4*)(khi_g + base + r * 64 + c8) = (u32x4){h0[0], h0[1], h1[0], h1[1]};
    *(u32x4*)(klo_g + base + r * 64 + c8) = (u32x4){l0[0], l0[1], l1[0], l1[1]};
    cs[0] += f0.x; cs[1] += f0.y; cs[2] += f0.z; cs[3] += f0.w;
    cs[4] += f1.x; cs[5] += f1.y; cs[6] += f1.z; cs[7] += f1.w;
    float ssq = f0.x*f0.x + f0.y*f0.y + f0.z*f0.z + f0.w*f0.w
              + f1.x*f1.x + f1.y*f1.y + f1.z*f1.z + f1.w*f1.w;
    ssq += __shfl_xor(ssq, 1); ssq += __shfl_xor(ssq, 2); ssq += __shfl_xor(ssq, 4);
    if ((t & 7) == 0) rmax = fmaxf(rmax, ssq);
    const float* vp = v + base + r * 64 + c8;
    float4 g0 = *(const float4*)vp;
    float4 g1 = *(const float4*)(vp + 4);
    vt[(c8 + 0) * 65 + r] = g0.x;
    vt[(c8 + 1) * 65 + r] = g0.y;
    vt[(c8 + 2) * 65 + r] = g0.z;
    vt[(c8 + 3) * 65 + r] = g0.w;
    vt[(c8 + 4) * 65 + r] = g1.x;
    vt[(c8 + 5) * 65 + r] = g1.y;
    vt[(c8 + 6) * 65 + r] = g1.z;
    vt[(c8 + 7) * 65 + r] = g1.w;
  }
  if ((t & 7) == 0) atomicMax(&bmaxS, __float_as_uint(rmax));
  // column-sum reduce over r-groups: xor 8/16/32 keep lane&7 (the column group)
#pragma unroll
  for (int i = 0; i < 8; ++i) {
    cs[i] += __shfl_xor(cs[i], 8);
    cs[i] += __shfl_xor(cs[i], 16);
    cs[i] += __shfl_xor(cs[i], 32);
  }
  if (lane < 8) {
    *(float4*)&pk_[w][lane * 8]     = (float4){cs[0], cs[1], cs[2], cs[3]};
    *(float4*)&pk_[w][lane * 8 + 4] = (float4){cs[4], cs[5], cs[6], cs[7]};
  }
  __syncthreads();
  if (t < 64) ksum[(size_t)blk * 64 + t] = pk_[0][t] + pk_[1][t] + pk_[2][t] + pk_[3][t];
  if (t == 0) kbmax[blk] = __uint_as_float(bmaxS);
#pragma unroll
  for (int it = 0; it < 2; ++it) {
    int idx = t + 256 * it, d = idx >> 3, s8 = (idx & 7) * 8;
    const float* vr = &vt[d * 65 + s8];
    float4 f0 = {vr[0], vr[1], vr[2], vr[3]};
    float4 f1 = {vr[4], vr[5], vr[6], vr[7]};
    u32x2 h0, l0, h1, l1;
    split4(f0, h0, l0); split4(f1, h1, l1);
    size_t o = (size_t)bh * 131072 + (size_t)d * 2048 + j * 64 + s8;
    *(u32x4*)(vthi_g + o) = (u32x4){h0[0], h0[1], h1[0], h1[1]};
    *(u32x4*)(vtlo_g + o) = (u32x4){l0[0], l0[1], l1[0], l1[1]};
  }
}

// ---------------------------------------------------------------------------
// k_attn: ONE q-block per WG, waves split K-rows (no load duplication).
// launch_bounds(256,3): unified VGPR budget ~170 -> spill-free (R3/R4 spilled
// at the 128 budget of (256,4): VGPR=64 + ~25 MB scratch writes).
// P and Q-lo tiles: [64 rows][128 B] XOR-swizzled (swz) -> 2 lanes/bank.
// Single-buffered P + 2 barriers/j; K prefetched across j; V issued early.
// LDS map (bytes), total 24608:
//   P hi 0..8192 | P lo 8192..16384   (overlay, dead before Pass B:
//     rbm u32[64*33] @0 (8448), lpart[4][64] @8448, qm[64] @9472,
//     MS[64] @9728, linv[64] @9984)
//   Qlo @16384..24576 (live whole kernel)   flg @24576
// ---------------------------------------------------------------------------
__global__ __launch_bounds__(256, 3) void k_attn(
    const float* __restrict__ q,
    const float* __restrict__ ksum,
    const u16* __restrict__ khi_g, const u16* __restrict__ klo_g,
    const u16* __restrict__ vthi_g, const u16* __restrict__ vtlo_g,
    const float* __restrict__ cdfthreshd, const float* __restrict__ simthreshd1,
    const float* __restrict__ pvthreshd, const float* __restrict__ kbmax,
    float* __restrict__ out) {
  int blk0 = blockIdx.x;
  int blk = (blk0 & 7) * 128 + (blk0 >> 3);   // bijective: 1024 % 8 == 0
  int bh = blk >> 5, iq = blk & 31, h = bh & (H - 1);
  int t = threadIdx.x, lane = t & 63, w = t >> 6;
  int m16 = lane & 15, quad = lane >> 4;

  __shared__ __align__(16) uint8_t smem[24608];
  uint8_t* phB = smem;                          // P hi tile (swizzled)
  uint8_t* plB = smem + 8192;                   // P lo tile
  uint8_t* qloB = smem + 16384;                 // Q-lo tile
  u32*   rbm   = (u32*)smem;                    // overlay: [64][33] u32 keys
  float* lpart = (float*)(smem + 8448);         // [4][64]
  float* qmS   = (float*)(smem + 9472);         // [64]
  float* MSs   = (float*)(smem + 9728);         // [64]
  float* linvS = (float*)(smem + 9984);         // [64]
  int*   flg   = (int*)(smem + 24576);          // [0]=pooled [1]=mw [2]=gm [3]=kmax2

  const float* qg = q + ((size_t)bh * L + (size_t)iq * 64) * D;
  const u16* kh = khi_g + (size_t)bh * (L * D);
  const u16* kl = klo_g + (size_t)bh * (L * D);
  const u16* vh = vthi_g + (size_t)bh * (L * D);
  const u16* vl = vtlo_g + (size_t)bh * (L * D);

  // ---- Q B-frags: hi -> registers (32 VGPR), lo -> swizzled LDS tile ----
  s16x8 qhf[4][2];
#pragma unroll
  for (int nt = 0; nt < 4; ++nt)
#pragma unroll
    for (int ks = 0; ks < 2; ++ks) {
      const float* p0 = qg + (size_t)(16 * nt + m16) * 64 + ks * 32 + quad * 8;
      float4 a = *(const float4*)p0;
      float4 b2 = *(const float4*)(p0 + 4);
      u32x2 ha, la, hb, lb;
      split4(a, ha, la); split4(b2, hb, lb);
      FragU fh;
      fh.u[0] = ha[0]; fh.u[1] = ha[1]; fh.u[2] = hb[0]; fh.u[3] = hb[1];
      qhf[nt][ks] = fh.v;
      if (w == 0)
        *(u32x4*)(qloB + swz(16 * nt + m16, ks * 64 + quad * 16)) =
            (u32x4){la[0], la[1], lb[0], lb[1]};
    }
  for (int e = t; e < 64 * 33; e += 256) rbm[e] = 0x7F800000u;

  // ---- phase 1: qm (w0), kmax2 (w1) ----
  if (w == 0) {
    float s = 0.f;
    for (int r = 0; r < 64; ++r) s += qg[r * 64 + lane];
    qmS[lane] = s * (1.f / 64.f);
  }
  if (w == 1) {
    float m = (lane < 32) ? kbmax[bh * 32 + lane] : 0.f;
    for (int off = 16; off; off >>= 1) m = fmaxf(m, __shfl_xor(m, off, 32));
    if (lane == 0) ((float*)flg)[3] = m;
  }
  __syncthreads();

  // ---- phase 2: CDF keep (w0); pooled cos + M (w1) ----
  bool keepj = false;
  if (w == 0 && lane < 32) {
    int j = lane;
    const float* ksp = ksum + (size_t)bh * NB * 64 + j * 64;
    float sv = 0.f;
    for (int d = 0; d < 64; ++d) sv += qmS[d] * ksp[d];
    sv *= (1.f / 64.f) * 0.125f;
    float mx = sv;
    for (int off = 16; off; off >>= 1) mx = fmaxf(mx, __shfl_xor(mx, off, 32));
    float p = expf(sv - mx);
    float sum = p;
    for (int off = 16; off; off >>= 1) sum += __shfl_xor(sum, off, 32);
    p /= sum;
    float excl = 0.f;
    for (int u = 0; u < 32; ++u) {
      float pu = __shfl(p, u, 32);
      if ((pu > p) || (pu == p && u < j)) excl += pu;
    }
    keepj = excl < cdfthreshd[h];
  }
  if (w == 1) {
    int r = lane;
    float kmax2 = ((float*)flg)[3];
    float dot = 0.f, qn2 = 0.f, qmn2 = 0.f;
    for (int d = 0; d < 64; ++d) {
      float a = qg[r * 64 + d], b2 = qmS[d];
      dot += a * b2; qn2 += a * a; qmn2 += b2 * b2;
    }
    float cs = dot / (sqrtf(qn2) * sqrtf(qmn2) + 1e-6f);
    float su = cs;
    for (int off = 32; off; off >>= 1) su += __shfl_xor(su, off);
    if (lane == 0) flg[0] = (su * (1.f / 64.f)) > simthreshd1[h];
    MSs[r] = sqrtf(qn2 * kmax2) * 0.125f;  // M_r >= |s| (Cauchy-Schwarz)
  }
  __syncthreads();
  if (w == 0 && lane < 32) {
    bool bit = keepj || !flg[0] || (lane == 0);
    unsigned long long bal = __ballot(bit);
    if (lane == 0) flg[1] = (int)(u32)bal;
  }
  __syncthreads();
  u32 mw = (u32)flg[1];

  float Mq[4];
#pragma unroll
  for (int nt = 0; nt < 4; ++nt) Mq[nt] = MSs[16 * nt + m16];

  // ---- Pass A: wave w owns K-rows 16w..16w+15; K prefetched across j ----
  float lp[4] = {0.f, 0.f, 0.f, 0.f};
  {
    u32 rm = mw;
    int j = (int)__builtin_ctz(rm); rm &= rm - 1;
    s16x8 ka0[2], ka1[2];
    {
      const u16* kr0 = kh + (size_t)(j * 64 + 16 * w + m16) * 64 + quad * 8;
      const u16* kl0 = kl + (size_t)(j * 64 + 16 * w + m16) * 64 + quad * 8;
#pragma unroll
      for (int ks = 0; ks < 2; ++ks) {
        ka0[ks] = *(const s16x8*)(kr0 + ks * 32);
        ka1[ks] = *(const s16x8*)(kl0 + ks * 32);
      }
    }
    for (;;) {
      f32x4 acc[4];
#pragma unroll
      for (int nt = 0; nt < 4; ++nt) acc[nt] = (f32x4){0.f, 0.f, 0.f, 0.f};
#pragma unroll
      for (int ks = 0; ks < 2; ++ks) {
        s16x8 ql_[4];
#pragma unroll
        for (int nt = 0; nt < 4; ++nt)
          ql_[nt] = *(const s16x8*)(qloB + swz(16 * nt + m16, ks * 64 + quad * 16));
        __builtin_amdgcn_s_setprio(1);
#pragma unroll
        for (int nt = 0; nt < 4; ++nt) {
          acc[nt] = __builtin_amdgcn_mfma_f32_16x16x32_bf16(ka0[ks], qhf[nt][ks], acc[nt], 0, 0, 0);
          acc[nt] = __builtin_amdgcn_mfma_f32_16x16x32_bf16(ka1[ks], qhf[nt][ks], acc[nt], 0, 0, 0);
          acc[nt] = __builtin_amdgcn_mfma_f32_16x16x32_bf16(ka0[ks], ql_[nt], acc[nt], 0, 0, 0);
        }
        __builtin_amdgcn_s_setprio(0);
      }
      // prefetch next-j K while exp/reductions run
      int nj = -1;
      s16x8 kn0[2], kn1[2];
      if (rm) {
        nj = (int)__builtin_ctz(rm); rm &= rm - 1;
        const u16* nr = kh + (size_t)(nj * 64 + 16 * w + m16) * 64 + quad * 8;
        const u16* nl = kl + (size_t)(nj * 64 + 16 * w + m16) * 64 + quad * 8;
#pragma unroll
        for (int ks = 0; ks < 2; ++ks) {
          kn0[ks] = *(const s16x8*)(nr + ks * 32);
          kn1[ks] = *(const s16x8*)(nl + ks * 32);
        }
      }
#pragma unroll
      for (int nt = 0; nt < 4; ++nt) {
        float vmax = -1e30f;
#pragma unroll
        for (int reg = 0; reg < 4; ++reg) {
          float s = acc[nt][reg] * 0.125f - Mq[nt];
          lp[nt] += __expf(s);
          vmax = fmaxf(vmax, s);
        }
        vmax = fmaxf(vmax, __shfl_xor(vmax, 16));
        vmax = fmaxf(vmax, __shfl_xor(vmax, 32));
        if (quad == 0)
          atomicMin(rbm + (16 * nt + m16) * 33 + j, __float_as_uint(fmaxf(-vmax, 0.f)));
      }
      if (nj < 0) break;
#pragma unroll
      for (int ks = 0; ks < 2; ++ks) { ka0[ks] = kn0[ks]; ka1[ks] = kn1[ks]; }
      j = nj;
    }
  }
#pragma unroll
  for (int nt = 0; nt < 4; ++nt) {
    float s = lp[nt];
    s += __shfl_xor(s, 16); s += __shfl_xor(s, 32);
    if (quad == 0) lpart[w * 64 + 16 * nt + m16] = s;
  }
  __syncthreads();
  if (t < 64) linvS[t] = 1.f / (lpart[t] + lpart[64 + t] + lpart[128 + t] + lpart[192 + t]);
  __syncthreads();

  // ---- PV gate (w0) ----
  if (w == 0 && lane < 32) {
    bool keep = (mw >> lane) & 1u;
    if (keep && lane != 0) {
      float thr = pvthreshd[h] * 1e-3f;
      float mp = 0.f;
      for (int r = 0; r < 64; ++r) {
        float key = __uint_as_float(rbm[r * 33 + lane]);
        mp = fmaxf(mp, __expf(-key) * linvS[r]);
      }
      keep = mp >= thr;
    }
    unsigned long long bal = __ballot(keep);
    if (lane == 0) flg[2] = (int)(u32)bal;
  }
  __syncthreads();
  u32 gm = (u32)flg[2];

  float linq[4];
#pragma unroll
  for (int nt = 0; nt < 4; ++nt) linq[nt] = linvS[16 * nt + m16];

  // ---- Pass B: single-buffer P, 2 barriers/j, K prefetch, early V ----
  f32x4 oacc[4];
#pragma unroll
  for (int nt = 0; nt < 4; ++nt) oacc[nt] = (f32x4){0.f, 0.f, 0.f, 0.f};
  {
    u32 rg = gm;
    int j = (int)__builtin_ctz(rg); rg &= rg - 1;   // gm always has sink bit 0
    s16x8 ka0[2], ka1[2];
    {
      const u16* kr0 = kh + (size_t)(j * 64 + 16 * w + m16) * 64 + quad * 8;
      const u16* kl0 = kl + (size_t)(j * 64 + 16 * w + m16) * 64 + quad * 8;
#pragma unroll
      for (int ks = 0; ks < 2; ++ks) {
        ka0[ks] = *(const s16x8*)(kr0 + ks * 32);
        ka1[ks] = *(const s16x8*)(kl0 + ks * 32);
      }
    }
    for (;;) {
      // S: wave's 16 K-rows x 64 q
      f32x4 acc[4];
#pragma unroll
      for (int nt = 0; nt < 4; ++nt) acc[nt] = (f32x4){0.f, 0.f, 0.f, 0.f};
#pragma unroll
      for (int ks = 0; ks < 2; ++ks) {
        s16x8 ql_[4];
#pragma unroll
        for (int nt = 0; nt < 4; ++nt)
          ql_[nt] = *(const s16x8*)(qloB + swz(16 * nt + m16, ks * 64 + quad * 16));
        __builtin_amdgcn_s_setprio(1);
#pragma unroll
        for (int nt = 0; nt < 4; ++nt) {
          acc[nt] = __builtin_amdgcn_mfma_f32_16x16x32_bf16(ka0[ks], qhf[nt][ks], acc[nt], 0, 0, 0);
          acc[nt] = __builtin_amdgcn_mfma_f32_16x16x32_bf16(ka1[ks], qhf[nt][ks], acc[nt], 0, 0, 0);
          acc[nt] = __builtin_amdgcn_mfma_f32_16x16x32_bf16(ka0[ks], ql_[nt], acc[nt], 0, 0, 0);
        }
        __builtin_amdgcn_s_setprio(0);
      }
      // prefetch next-j K (covered by exp + P-write + barrier + PV)
      int nj = -1;
      s16x8 kn0[2], kn1[2];
      if (rg) {
        nj = (int)__builtin_ctz(rg); rg &= rg - 1;
        const u16* nr = kh + (size_t)(nj * 64 + 16 * w + m16) * 64 + quad * 8;
        const u16* nl = kl + (size_t)(nj * 64 + 16 * w + m16) * 64 + quad * 8;
#pragma unroll
        for (int ks = 0; ks < 2; ++ks) {
          kn0[ks] = *(const s16x8*)(nr + ks * 32);
          kn1[ks] = *(const s16x8*)(nl + ks * 32);
        }
      }
      __syncthreads();   // prior PV reads of P complete; safe to overwrite
      // P = exp(S-M)*linv -> split -> swizzled P[qrow][kcol]
#pragma unroll
      for (int nt = 0; nt < 4; ++nt) {
        float4 pv;
        pv.x = __expf(acc[nt][0] * 0.125f - Mq[nt]) * linq[nt];
        pv.y = __expf(acc[nt][1] * 0.125f - Mq[nt]) * linq[nt];
        pv.z = __expf(acc[nt][2] * 0.125f - Mq[nt]) * linq[nt];
        pv.w = __expf(acc[nt][3] * 0.125f - Mq[nt]) * linq[nt];
        u32x2 hi, lo; split4(pv, hi, lo);
        int off = swz(16 * nt + m16, 32 * w + 8 * quad);
        *(u32x2*)(phB + off) = hi;
        *(u32x2*)(plB + off) = lo;
      }
      // V^T A-frags for current j (consumed after the barrier)
      s16x8 va0[2], va1[2];
      {
        const u16* vr0 = vh + (size_t)(16 * w + m16) * L + j * 64 + quad * 8;
        const u16* vl0 = vl + (size_t)(16 * w + m16) * L + j * 64 + quad * 8;
#pragma unroll
        for (int ks = 0; ks < 2; ++ks) {
          va0[ks] = *(const s16x8*)(vr0 + ks * 32);
          va1[ks] = *(const s16x8*)(vl0 + ks * 32);
        }
      }
      __syncthreads();   // P complete
      // PV: A = V^T rows 16w..16w+15, B = P frags from LDS
#pragma unroll
      for (int ks = 0; ks < 2; ++ks)
#pragma unroll
        for (int nt = 0; nt < 4; ++nt) {
          s16x8 pbh = *(const s16x8*)(phB + swz(16 * nt + m16, ks * 64 + quad * 16));
          s16x8 pbl = *(const s16x8*)(plB + swz(16 * nt + m16, ks * 64 + quad * 16));
          __builtin_amdgcn_s_setprio(1);
          oacc[nt] = __builtin_amdgcn_mfma_f32_16x16x32_bf16(va0[ks], pbh, oacc[nt], 0, 0, 0);
          oacc[nt] = __builtin_amdgcn_mfma_f32_16x16x32_bf16(va1[ks], pbh, oacc[nt], 0, 0, 0);
          oacc[nt] = __builtin_amdgcn_mfma_f32_16x16x32_bf16(va0[ks], pbl, oacc[nt], 0, 0, 0);
          __builtin_amdgcn_s_setprio(0);
        }
      if (nj < 0) break;
#pragma unroll
      for (int ks = 0; ks < 2; ++ks) { ka0[ks] = kn0[ks]; ka1[ks] = kn1[ks]; }
      j = nj;
    }
  }

  // ---- store O: lane -> qrow = 16nt+m16, d = 16w+4quad (f32x4 over reg) ----
  float* ob = out + ((size_t)bh * L + (size_t)iq * 64) * D;
#pragma unroll
  for (int nt = 0; nt < 4; ++nt)
    *(f32x4*)(ob + (size_t)(16 * nt + m16) * 64 + 16 * w + 4 * quad) = oacc[nt];
}

// ---------------------------------------------------------------------------
extern "C" void kernel_launch(void* const* d_in, const int* in_sizes, int n_in,
                              void* d_out, int out_size, void* d_ws, size_t ws_size,
                              hipStream_t stream) {
  (void)in_sizes; (void)n_in; (void)out_size; (void)ws_size;
  const float* q   = (const float*)d_in[0];
  const float* k   = (const float*)d_in[1];
  const float* v   = (const float*)d_in[2];
  const float* cdf = (const float*)d_in[3];
  const float* sim = (const float*)d_in[4];
  const float* pvt = (const float*)d_in[5];
  float* out = (float*)d_out;

  uint8_t* w8 = (uint8_t*)d_ws;
  float* ksum  = (float*)w8;                          // 1024*64 f (256 KB)
  float* kbmax = (float*)(w8 + 262144);               // 1024 f (4 KB)
  u16* khi_g  = (u16*)(w8 + 266240);                  // 4 planes x 8 MB
  u16* klo_g  = khi_g + (size_t)B * H * L * D;
  u16* vthi_g = klo_g + (size_t)B * H * L * D;
  u16* vtlo_g = vthi_g + (size_t)B * H * L * D;

  k_prep<<<B * H * NB, 256, 0, stream>>>(k, v, ksum, khi_g, klo_g, vthi_g, vtlo_g, kbmax);
  k_attn<<<B * H * NB, 256, 0, stream>>>(q, ksum, khi_g, klo_g, vthi_g, vtlo_g,
                                         cdf, sim, pvt, kbmax, out);
}